// Round 4
// baseline (502.477 us; speedup 1.0000x reference)
//
#include <hip/hip_runtime.h>

#define BATCH 8
#define LT 4096
#define LV 4096
#define DIM 1024
#define TOPK 8

// ---------------------------------------------------------------------------
// k1: fused (a) squared-row-norms of text_feats, (b) zero-fill of the padded
// output region (rows 8..4095 of both outputs). The final kernel writes rows
// 0..7 — disjoint, so ordering vs k_attn doesn't matter.
// blocks [0,8192): norms, 4 rows/block (1 wave per row)
// blocks [8192,10240): zero fill, 16 segments x 128 blocks
// ---------------------------------------------------------------------------
__global__ __launch_bounds__(256) void k_norm_zero(const float* __restrict__ tf,
                                                   float* __restrict__ norms,
                                                   float* __restrict__ out) {
    int blk = blockIdx.x;
    if (blk < 8192) {
        int wave = threadIdx.x >> 6;
        int lane = threadIdx.x & 63;
        int row  = blk * 4 + wave;              // 0..32767
        const float4* p = (const float4*)(tf + (size_t)row * DIM);
        float acc = 0.f;
#pragma unroll
        for (int j = 0; j < 4; ++j) {
            float4 v = p[lane + 64 * j];
            acc += v.x * v.x + v.y * v.y + v.z * v.z + v.w * v.w;
        }
#pragma unroll
        for (int o = 32; o > 0; o >>= 1) acc += __shfl_down(acc, o, 64);
        if (lane == 0) norms[row] = acc;        // squared norm: same ordering as norm
    } else {
        int zb  = blk - 8192;
        int seg = zb & 15;                      // 16 segments (8 text + 8 visual batches)
        int sub = zb >> 4;                      // 128 blocks per segment
        // segment s: floats [s*4194304 + 8192, s*4194304 + 4194304)
        float4* base = (float4*)out + (size_t)seg * 1048576 + 2048;
        const int len = 1046528;                // 4088*1024/4 float4s
        float4 z = make_float4(0.f, 0.f, 0.f, 0.f);
        for (int i = sub * 256 + (int)threadIdx.x; i < len; i += 128 * 256)
            base[i] = z;
    }
}

// ---------------------------------------------------------------------------
// k2: per-batch top-8 of the 4096 scores. 8 iterations of argmax with
// jax.lax.top_k tie-breaking (smaller index wins on equal value).
// ---------------------------------------------------------------------------
__global__ __launch_bounds__(256) void k_topk(const float* __restrict__ norms,
                                              int* __restrict__ idx_out) {
    __shared__ float s[LT];
    __shared__ float rv[256];
    __shared__ int   ri[256];
    int b = blockIdx.x, tid = threadIdx.x;
    for (int i = tid; i < LT; i += 256) s[i] = norms[b * LT + i];
    __syncthreads();
    for (int r = 0; r < TOPK; ++r) {
        float bv = -2.f; int bi = 0x7fffffff;
        for (int i = tid; i < LT; i += 256) {   // ascending i -> keeps smallest idx on ties
            float v = s[i];
            if (v > bv) { bv = v; bi = i; }
        }
        rv[tid] = bv; ri[tid] = bi;
        __syncthreads();
        for (int o = 128; o > 0; o >>= 1) {
            if (tid < o) {
                float v2 = rv[tid + o]; int i2 = ri[tid + o];
                if (v2 > rv[tid] || (v2 == rv[tid] && i2 < ri[tid])) {
                    rv[tid] = v2; ri[tid] = i2;
                }
            }
            __syncthreads();
        }
        if (tid == 0) { idx_out[b * TOPK + r] = ri[0]; s[ri[0]] = -1.f; }
        __syncthreads();
    }
}

// ---------------------------------------------------------------------------
// k3a: tq[b][t][d] = b_key[d] + sum_k text_keys[b][t][k] * W[d][k]
// grid (16 d-chunks of 64, 8 batches). text_keys staged in LDS; W rows stay
// L2-resident across batches (same chunk reads same 64 rows).
// ---------------------------------------------------------------------------
__global__ __launch_bounds__(256) void k_tq(const float* __restrict__ tf,
                                            const float* __restrict__ W,
                                            const float* __restrict__ bias,
                                            const int* __restrict__ idx,
                                            float* __restrict__ tq) {
    int b = blockIdx.y;
    int chunk = blockIdx.x;
    __shared__ float tk[TOPK][DIM];
    for (int t = 0; t < TOPK; ++t) {
        const float4* src = (const float4*)(tf + ((size_t)b * LT + idx[b * TOPK + t]) * DIM);
        float4* dst = (float4*)tk[t];
        for (int i = threadIdx.x; i < DIM / 4; i += 256) dst[i] = src[i];
    }
    __syncthreads();
    int dloc = threadIdx.x & 63;
    int tp   = threadIdx.x >> 6;                // wave id: handles rows tp and tp+4
    int d = chunk * 64 + dloc;
    const float4* wrow = (const float4*)(W + (size_t)d * DIM);
    const float4* tk0  = (const float4*)tk[tp];
    const float4* tk1  = (const float4*)tk[tp + 4];
    float acc0 = 0.f, acc1 = 0.f;
    for (int k = 0; k < DIM / 4; ++k) {
        float4 w = wrow[k];
        float4 a = tk0[k], c = tk1[k];          // LDS broadcast (wave-uniform addr)
        acc0 += w.x * a.x + w.y * a.y + w.z * a.z + w.w * a.w;
        acc1 += w.x * c.x + w.y * c.y + w.z * c.z + w.w * c.w;
    }
    float bb = bias[d];
    tq[(b * TOPK + tp) * DIM + d]     = acc0 + bb;
    tq[(b * TOPK + tp + 4) * DIM + d] = acc1 + bb;
}

// ---------------------------------------------------------------------------
// k3b: sim -> softmax -> text_out rows 0..7 and visual_out rows 0..7.
// One block per batch.
// ---------------------------------------------------------------------------
__global__ __launch_bounds__(256) void k_attn(const float* __restrict__ tf,
                                              const float* __restrict__ vf,
                                              const float* __restrict__ tq,
                                              const int* __restrict__ idx,
                                              float* __restrict__ out) {
    int b = blockIdx.x, tid = threadIdx.x;
    __shared__ float vk[TOPK][DIM];             // 32 KB
    __shared__ float sim[TOPK][TOPK];
    __shared__ float he[TOPK][TOPK];
    {   // stage visual_keys = visual_feats[b, :8, :]
        const float4* src = (const float4*)(vf + (size_t)b * LV * DIM);
        float4* dst = (float4*)vk;
        for (int i = tid; i < TOPK * DIM / 4; i += 256) dst[i] = src[i];
    }
    __syncthreads();
    // sim[t][v]: 4 waves x 16 (t,v) pairs, 64-lane dot + shuffle reduce
    int wave = tid >> 6, lane = tid & 63;
    for (int p = wave * 16; p < wave * 16 + 16; ++p) {
        int t = p >> 3, v = p & 7;
        const float4* q  = (const float4*)(tq + (b * TOPK + t) * DIM);
        const float4* vv = (const float4*)vk[v];
        float acc = 0.f;
#pragma unroll
        for (int j = 0; j < 4; ++j) {
            float4 a = q[lane + 64 * j];
            float4 c = vv[lane + 64 * j];
            acc += a.x * c.x + a.y * c.y + a.z * c.z + a.w * c.w;
        }
#pragma unroll
        for (int o = 32; o > 0; o >>= 1) acc += __shfl_down(acc, o, 64);
        if (lane == 0) sim[t][v] = acc;
    }
    __syncthreads();
    if (tid < TOPK) {                           // softmax over v for row tid
        float m = -1e30f;
#pragma unroll
        for (int v = 0; v < TOPK; ++v) m = fmaxf(m, sim[tid][v]);
        float e[TOPK], ssum = 0.f;
#pragma unroll
        for (int v = 0; v < TOPK; ++v) { e[v] = expf(sim[tid][v] - m); ssum += e[v]; }
        float inv = 1.f / ssum;
#pragma unroll
        for (int v = 0; v < TOPK; ++v) he[tid][v] = e[v] * inv;
    }
    __syncthreads();
    float* to = out + (size_t)b * LT * DIM;               // text_out batch base
    float* vo = out + (size_t)(BATCH + b) * LT * DIM;     // visual_out batch base
    // text_out[t][d] = sum_v he[t][v] * vk[v][d]
    for (int i = tid; i < TOPK * DIM; i += 256) {
        int t = i >> 10, d = i & 1023;
        float acc = 0.f;
#pragma unroll
        for (int v = 0; v < TOPK; ++v) acc += he[t][v] * vk[v][d];
        to[t * DIM + d] = acc;
    }
    // visual_out[v][d] = sum_t he[t][v] * text_keys[t][d]  (rows re-read, L2-hot)
    const float* tfb = tf + (size_t)b * LT * DIM;
    int rows[TOPK];
#pragma unroll
    for (int t = 0; t < TOPK; ++t) rows[t] = idx[b * TOPK + t];
    for (int i = tid; i < TOPK * DIM; i += 256) {
        int v = i >> 10, d = i & 1023;
        float acc = 0.f;
#pragma unroll
        for (int t = 0; t < TOPK; ++t) acc += he[t][v] * tfb[(size_t)rows[t] * DIM + d];
        vo[v * DIM + d] = acc;
    }
}

extern "C" void kernel_launch(void* const* d_in, const int* in_sizes, int n_in,
                              void* d_out, int out_size, void* d_ws, size_t ws_size,
                              hipStream_t stream) {
    const float* tf   = (const float*)d_in[0];  // text_feats  (8,4096,1024)
    const float* vf   = (const float*)d_in[1];  // visual_feats(8,4096,1024)
    const float* W    = (const float*)d_in[2];  // W_key (1024,1024)
    const float* bias = (const float*)d_in[3];  // b_key (1024,)
    float* out = (float*)d_out;
    float* ws  = (float*)d_ws;
    float* norms = ws;                          // 32768 floats
    int*   idx   = (int*)(ws + 32768);          // 64 ints
    float* tq    = ws + 32768 + 64;             // 65536 floats (16B-aligned offset)

    k_norm_zero<<<10240, 256, 0, stream>>>(tf, norms, out);
    k_topk<<<8, 256, 0, stream>>>(norms, idx);
    k_tq<<<dim3(16, 8), 256, 0, stream>>>(tf, W, bias, idx, tq);
    k_attn<<<8, 256, 0, stream>>>(tf, vf, tq, idx, out);
}